// Round 5
// baseline (646.184 us; speedup 1.0000x reference)
//
#include <hip/hip_runtime.h>
#include <hip/hip_bf16.h>
#include <stdint.h>

#define K_NB    50
#define DELTA   1e-3f
#define NKEYS   200000
#define BROWS   1024
#define HDIM    64
#define SDIM    256
#define ADIM    18
#define NS      80          // pre-selection width (exact top-50 subset, covers q16 reorder)
#define XB      96          // x-blocks in k_dist -> 768 blocks = 3 blocks/CU
#define JMAX    17          // ceil(NTILES/XB)
#define NTILES  1563        // ceil(200000/128)

// out layout (floats): policy [0,18432) | value [18432,19456) | h [19456,84992)
#define OUT_VAL_OFF 18432
#define OUT_H_OFF   19456

typedef __attribute__((ext_vector_type(8))) short short8;
typedef __attribute__((ext_vector_type(4))) float f32x4;
typedef unsigned long long ull;

__device__ __forceinline__ unsigned ford(float f) {
    unsigned u = __float_as_uint(f);
    return (u & 0x80000000u) ? ~u : (u | 0x80000000u);
}
__device__ __forceinline__ float funord(unsigned u) {
    u = (u & 0x80000000u) ? (u & 0x7FFFFFFFu) : ~u;
    return __uint_as_float(u);
}
__device__ __forceinline__ unsigned short bf16_rne(float f) {
    unsigned u = __float_as_uint(f);
    unsigned r = u + 0x7FFFu + ((u >> 16) & 1u);
    return (unsigned short)(r >> 16);
}
__device__ __forceinline__ float bf16_tof(unsigned short b) {
    return __uint_as_float(((unsigned)b) << 16);
}

// ---------- K1: h = relu(x@W1+b1), hsq, policy, A2 bf16 hi/lo, zero ovcnt ----------
__global__ __launch_bounds__(64) void k_mlp(
    const float* __restrict__ x, const float* __restrict__ W1,
    const float* __restrict__ b1, const float* __restrict__ Wp,
    const float* __restrict__ bp, float* __restrict__ out,
    float* __restrict__ ws_h, float* __restrict__ hsq,
    unsigned* __restrict__ ovcnt, unsigned short* __restrict__ a2)
{
    const int b = blockIdx.x;
    const int j = threadIdx.x;
    const float* xr = x + b * SDIM;
    float a0 = 0.f, a1 = 0.f, a2r = 0.f, a3 = 0.f;
    #pragma unroll 8
    for (int s = 0; s < SDIM; s += 4) {
        a0  = fmaf(xr[s+0], W1[(s+0)*HDIM + j], a0);
        a1  = fmaf(xr[s+1], W1[(s+1)*HDIM + j], a1);
        a2r = fmaf(xr[s+2], W1[(s+2)*HDIM + j], a2r);
        a3  = fmaf(xr[s+3], W1[(s+3)*HDIM + j], a3);
    }
    float h = (a0 + a1) + (a2r + a3) + b1[j];
    h = fmaxf(h, 0.f);
    ws_h[b*HDIM + j] = h;
    out[OUT_H_OFF + b*HDIM + j] = h;

    unsigned u = __float_as_uint(h);
    unsigned short hi = (unsigned short)(u >> 16);        // trunc split
    float lf = h - __uint_as_float(u & 0xFFFF0000u);
    unsigned short lo = bf16_rne(lf);
    a2[b*128 + j]      = hi;
    a2[b*128 + 64 + j] = lo;

    float sq = h * h;
    #pragma unroll
    for (int m = 32; m >= 1; m >>= 1) sq += __shfl_xor(sq, m, 64);
    if (j == 0) { hsq[b] = sq; ovcnt[b] = 0u; }

    __shared__ float hl[HDIM];
    hl[j] = h;
    __syncthreads();
    if (j < ADIM) {
        float p = bp[j];
        #pragma unroll 8
        for (int k = 0; k < HDIM; k++) p = fmaf(hl[k], Wp[k*ADIM + j], p);
        out[b*ADIM + j] = p;
    }
}

// ---------- K2: ksq ----------
__global__ __launch_bounds__(256) void k_ksq(
    const float* __restrict__ keys, float* __restrict__ ksq)
{
    const int t = threadIdx.x;
    const int key = blockIdx.x * 16 + (t >> 4);
    const int l = t & 15;
    float4 v = *(const float4*)(keys + (size_t)key * HDIM + l * 4);
    float s = v.x*v.x + v.y*v.y + v.z*v.z + v.w*v.w;
    s += __shfl_xor(s, 1, 64);
    s += __shfl_xor(s, 2, 64);
    s += __shfl_xor(s, 4, 64);
    s += __shfl_xor(s, 8, 64);
    if (l == 0) ksq[key] = s;
}

// ---------- K3a: sample distance GEMM -> u16 quantized d, one tile per block ----------
__global__ __launch_bounds__(256, 2) void k_sdist(
    const float* __restrict__ keys, const unsigned short* __restrict__ a2,
    const float* __restrict__ hsq, const float* __restrict__ ksq,
    unsigned short* __restrict__ d_sample, int sample)
{
    __shared__ short8 Bl[16][130];   // g-stride == 8 banks mod 32: 2-way reads (free)

    const int t    = threadIdx.x;
    const int w    = t >> 6;
    const int lane = t & 63;
    const int wr0  = (w >> 1) * 64;
    const int wc0  = (w & 1) * 64;
    const int l15  = lane & 15;
    const int l4   = lane >> 4;
    const int row0 = blockIdx.y * 128;
    const int n0   = blockIdx.x * 128;

    short8 a[4][4];
    #pragma unroll
    for (int mf = 0; mf < 4; mf++) {
        int row = row0 + wr0 + mf * 16 + l15;
        #pragma unroll
        for (int at = 0; at < 4; at++)
            a[mf][at] = *(const short8*)(a2 + (size_t)row * 128 + at * 32 + l4 * 8);
    }
    float hs_r[4][4];
    #pragma unroll
    for (int mf = 0; mf < 4; mf++)
        #pragma unroll
        for (int rg = 0; rg < 4; rg++)
            hs_r[mf][rg] = hsq[row0 + wr0 + mf*16 + l4*4 + rg];

    const int skey  = t >> 1;
    const int spart = t & 1;
    float4 f[8];
    {
        const float4* kp = (const float4*)(keys + (size_t)(n0 + skey) * HDIM + spart * 32);
        #pragma unroll
        for (int i = 0; i < 8; i++) f[i] = kp[i];
    }
    short8 Hh[4], Ll[4];
    #pragma unroll
    for (int i = 0; i < 4; i++) {
        float fv[8] = { f[2*i].x, f[2*i].y, f[2*i].z, f[2*i].w,
                        f[2*i+1].x, f[2*i+1].y, f[2*i+1].z, f[2*i+1].w };
        #pragma unroll
        for (int q = 0; q < 8; q++) {
            unsigned u = __float_as_uint(fv[q]);
            Hh[i][q] = (short)(u >> 16);
            float lf = fv[q] - __uint_as_float(u & 0xFFFF0000u);
            Ll[i][q] = (short)(__float_as_uint(lf) >> 16);
        }
    }
    #pragma unroll
    for (int i = 0; i < 4; i++) {
        Bl[spart*4 + i][skey]     = Hh[i];
        Bl[8 + spart*4 + i][skey] = Ll[i];
    }
    __syncthreads();

    float kh[4];
    #pragma unroll
    for (int nf = 0; nf < 4; nf++)
        kh[nf] = 0.5f * ksq[n0 + wc0 + nf * 16 + l15];

    f32x4 acc[4][4];
    #pragma unroll
    for (int mf = 0; mf < 4; mf++)
        #pragma unroll
        for (int nf = 0; nf < 4; nf++)
            acc[mf][nf] = (f32x4){0.f,0.f,0.f,0.f};

    #pragma unroll
    for (int bt = 0; bt < 4; bt++) {
        short8 bf[4];
        #pragma unroll
        for (int nf = 0; nf < 4; nf++)
            bf[nf] = Bl[bt*4 + l4][wc0 + nf*16 + l15];
        const int at0 = (bt < 2) ? bt : (bt - 2);
        #pragma unroll
        for (int mf = 0; mf < 4; mf++)
            #pragma unroll
            for (int nf = 0; nf < 4; nf++)
                acc[mf][nf] = __builtin_amdgcn_mfma_f32_16x16x32_bf16(
                    a[mf][at0], bf[nf], acc[mf][nf], 0, 0, 0);
        if (bt < 2) {
            const int at1 = bt + 2;
            #pragma unroll
            for (int mf = 0; mf < 4; mf++)
                #pragma unroll
                for (int nf = 0; nf < 4; nf++)
                    acc[mf][nf] = __builtin_amdgcn_mfma_f32_16x16x32_bf16(
                        a[mf][at1], bf[nf], acc[mf][nf], 0, 0, 0);
        }
    }

    #pragma unroll
    for (int mf = 0; mf < 4; mf++)
        #pragma unroll
        for (int nf = 0; nf < 4; nf++)
            #pragma unroll
            for (int rg = 0; rg < 4; rg++) {
                int row = row0 + wr0 + mf*16 + l4*4 + rg;
                int col = n0 + wc0 + nf*16 + l15;
                float s = kh[nf] - acc[mf][nf][rg];
                float d = fmaf(2.f, s, hs_r[mf][rg]);
                d_sample[(size_t)row * sample + col] = (unsigned short)(ford(d) >> 16);
            }
}

// ---------- K3b: rank-select threshold from quantized sample distances ----------
__global__ __launch_bounds__(256) void k_sel(
    const unsigned short* __restrict__ d_sample, float* __restrict__ thr,
    int sample, int rank)
{
    __shared__ unsigned sbuf[4][2048];     // up to 4096 u16 per row
    const int t = threadIdx.x;
    const int wv = t >> 6;
    const int l = t & 63;
    const int row = blockIdx.x * 4 + wv;

    const int nvec = sample >> 3;          // uint4 count per row
    const uint4* gp = (const uint4*)(d_sample + (size_t)row * sample);
    for (int q = 0; q < nvec / 64; q++) {
        uint4 vv = gp[l + 64*q];
        int bidx = (l + 64*q) * 4;
        sbuf[wv][bidx+0] = vv.x; sbuf[wv][bidx+1] = vv.y;
        sbuf[wv][bidx+2] = vv.z; sbuf[wv][bidx+3] = vv.w;
    }
    __syncthreads();

    const int nscan = sample >> 7;         // u32 words per lane
    float tval = 0.f;
    for (int it = 0; it < rank; it++) {
        unsigned best = 0xFFFFFFFFu;
        for (int m = 0; m < nscan; m++) {
            unsigned wd = sbuf[wv][l + 64*m];
            unsigned slot2 = (unsigned)((l + 64*m) * 2);
            unsigned klo = ((wd & 0xFFFFu) << 12) | slot2;
            unsigned khi = ((wd >> 16) << 12) | (slot2 + 1);
            unsigned kk = (klo < khi) ? klo : khi;
            best = (kk < best) ? kk : best;
        }
        #pragma unroll
        for (int m = 1; m < 64; m <<= 1) {
            unsigned o = __shfl_xor(best, m, 64);
            best = (o < best) ? o : best;
        }
        if (l == 0) {
            unsigned slot = best & 0xFFFu;
            unsigned wd = sbuf[wv][slot >> 1];
            wd |= (slot & 1) ? 0xFFFF0000u : 0x0000FFFFu;
            sbuf[wv][slot >> 1] = wd;
        }
        if (it == rank - 1) tval = funord((best >> 12) << 16);
        __syncthreads();
    }
    if (l == 0) thr[row] = tval;
}

// ---------- K4: MFMA split-bf16 distance GEMM, per-lane LDS-atomic candidates ----------
__global__ __launch_bounds__(256, 2) void k_dist(
    const float* __restrict__ keys, const unsigned short* __restrict__ a2,
    const float* __restrict__ hsq, const float* __restrict__ ksq,
    const float* __restrict__ thr, int* __restrict__ cnt2,
    unsigned* __restrict__ ovcnt, ull* __restrict__ ov,
    unsigned* __restrict__ cand, int cap, int ovcap)
{
    __shared__ short8 Bl[16][130];            // 33280 B
    __shared__ unsigned cand_lds[128 * 32];   // 16384 B
    __shared__ unsigned lds_cnt[128];         // 512 B  -> total 50176 B = 3 blocks/CU

    const int t    = threadIdx.x;
    const int w    = t >> 6;
    const int lane = t & 63;
    const int wr0  = (w >> 1) * 64;
    const int wc0  = (w & 1) * 64;
    const int l15  = lane & 15;
    const int l4   = lane >> 4;
    const int row0 = blockIdx.y * 128;
    const int bx   = blockIdx.x;

    if (t < 128) lds_cnt[t] = 0u;

    short8 a[4][4];
    #pragma unroll
    for (int mf = 0; mf < 4; mf++) {
        int row = row0 + wr0 + mf * 16 + l15;
        #pragma unroll
        for (int at = 0; at < 4; at++)
            a[mf][at] = *(const short8*)(a2 + (size_t)row * 128 + at * 32 + l4 * 8);
    }
    float lim[4][4];
    #pragma unroll
    for (int mf = 0; mf < 4; mf++)
        #pragma unroll
        for (int rg = 0; rg < 4; rg++) {
            int r = row0 + wr0 + mf * 16 + l4 * 4 + rg;
            lim[mf][rg] = (thr[r] - hsq[r]) * 0.5f;
        }

    const int skey  = t >> 1;
    const int spart = t & 1;
    float4 f[8];
    {
        const float4* kp = (const float4*)(keys + (size_t)(bx * 128 + skey) * HDIM + spart * 32);
        #pragma unroll
        for (int i = 0; i < 8; i++) f[i] = kp[i];
    }

    for (int j = 0; j < JMAX; j++) {
        const int cur = bx + j * XB;
        if (cur >= NTILES) break;

        short8 Hh[4], Ll[4];
        #pragma unroll
        for (int i = 0; i < 4; i++) {
            float fv[8] = { f[2*i].x, f[2*i].y, f[2*i].z, f[2*i].w,
                            f[2*i+1].x, f[2*i+1].y, f[2*i+1].z, f[2*i+1].w };
            #pragma unroll
            for (int q = 0; q < 8; q++) {
                unsigned u = __float_as_uint(fv[q]);
                Hh[i][q] = (short)(u >> 16);
                float lf = fv[q] - __uint_as_float(u & 0xFFFF0000u);
                Ll[i][q] = (short)(__float_as_uint(lf) >> 16);
            }
        }

        __syncthreads();             // (A) prev tile's Bl reads done
        #pragma unroll
        for (int i = 0; i < 4; i++) {
            Bl[spart*4 + i][skey]     = Hh[i];
            Bl[8 + spart*4 + i][skey] = Ll[i];
        }
        __syncthreads();             // (B) B tile ready

        // prefetch next tile: crosses no barrier until consumed next iter
        {
            int nxt = cur + XB;
            if (nxt < NTILES) {
                int kg = nxt * 128 + skey;
                if (kg < NKEYS) {
                    const float4* kp = (const float4*)(keys + (size_t)kg * HDIM + spart * 32);
                    #pragma unroll
                    for (int i = 0; i < 8; i++) f[i] = kp[i];
                } else {
                    #pragma unroll
                    for (int i = 0; i < 8; i++) f[i] = make_float4(0.f,0.f,0.f,0.f);
                }
            }
        }

        float kh[4];
        #pragma unroll
        for (int nf = 0; nf < 4; nf++) {
            int col = cur * 128 + wc0 + nf * 16 + l15;
            kh[nf] = (col < NKEYS) ? 0.5f * ksq[col] : 3.0e37f;
        }

        f32x4 acc[4][4];
        #pragma unroll
        for (int mf = 0; mf < 4; mf++)
            #pragma unroll
            for (int nf = 0; nf < 4; nf++)
                acc[mf][nf] = (f32x4){0.f,0.f,0.f,0.f};

        #pragma unroll
        for (int bt = 0; bt < 4; bt++) {
            short8 bf[4];
            #pragma unroll
            for (int nf = 0; nf < 4; nf++)
                bf[nf] = Bl[bt*4 + l4][wc0 + nf*16 + l15];
            const int at0 = (bt < 2) ? bt : (bt - 2);
            #pragma unroll
            for (int mf = 0; mf < 4; mf++)
                #pragma unroll
                for (int nf = 0; nf < 4; nf++)
                    acc[mf][nf] = __builtin_amdgcn_mfma_f32_16x16x32_bf16(
                        a[mf][at0], bf[nf], acc[mf][nf], 0, 0, 0);
            if (bt < 2) {
                const int at1 = bt + 2;
                #pragma unroll
                for (int mf = 0; mf < 4; mf++)
                    #pragma unroll
                    for (int nf = 0; nf < 4; nf++)
                        acc[mf][nf] = __builtin_amdgcn_mfma_f32_16x16x32_bf16(
                            a[mf][at1], bf[nf], acc[mf][nf], 0, 0, 0);
            }
        }

        // epilogue: per-lane LDS-atomic append (no ballot decode, no shfl)
        #pragma unroll
        for (int mf = 0; mf < 4; mf++)
            #pragma unroll
            for (int nf = 0; nf < 4; nf++)
                #pragma unroll
                for (int rg = 0; rg < 4; rg++) {
                    float s = kh[nf] - acc[mf][nf][rg];
                    if (s < lim[mf][rg]) {
                        int lrow = wr0 + mf*16 + l4*4 + rg;
                        unsigned pos = atomicAdd(&lds_cnt[lrow], 1u);
                        if (pos < (unsigned)cap) {
                            unsigned packed = (ford(s) & 0xFFFF0000u)
                                            | ((unsigned)j << 7)
                                            | (unsigned)(wc0 + nf*16 + l15);
                            cand_lds[lrow * 32 + pos] = packed;
                        } else {
                            int grow = row0 + lrow;
                            unsigned p2 = atomicAdd(&ovcnt[grow], 1u);
                            if (p2 < (unsigned)ovcap)
                                ov[(size_t)grow * ovcap + p2] =
                                    ((ull)ford(s) << 32) | (unsigned)(cur*128 + wc0 + nf*16 + l15);
                        }
                    }
                }
    }

    __syncthreads();
    // flush: contiguous, fully-dirty lines
    {
        const int lr   = t >> 1;
        const int half = t & 1;
        unsigned c = lds_cnt[lr];
        if (c > (unsigned)cap) c = (unsigned)cap;
        if (half == 0) cnt2[(size_t)(row0 + lr) * XB + bx] = (int)c;
        const int hc = cap >> 1;
        unsigned* dst = cand + ((size_t)(row0 + lr) * XB + bx) * cap + half * hc;
        const unsigned* src = &cand_lds[lr * 32 + half * hc];
        for (int i = 0; i < hc / 4; i++)
            ((uint4*)dst)[i] = *(const uint4*)&src[i * 4];
    }
}

// ---------- K5: gather -> approx top-NS -> exact recompute -> exact top-50 ----------
__global__ __launch_bounds__(384) void k_merge(
    const unsigned* __restrict__ cand, const int* __restrict__ cnt2,
    const unsigned* __restrict__ ovcnt, const ull* __restrict__ ov,
    const float* __restrict__ vals, const float* __restrict__ keys,
    const float* __restrict__ ws_h, const float* __restrict__ hsq,
    const float* __restrict__ ksq, float* __restrict__ out_val,
    int cap, int ovcap)
{
    __shared__ ull wred2[6];
    __shared__ ull win[NS];
    __shared__ float hrow_s[HDIM];
    __shared__ float dexs[NS];
    __shared__ unsigned idxs[NS];
    __shared__ float rs[6], rvs[6];

    const int r = blockIdx.x;
    const int t = threadIdx.x;

    if (t < HDIM) hrow_s[t] = ws_h[(size_t)r * HDIM + t];

    ull v[10];
    #pragma unroll
    for (int i = 0; i < 10; i++) v[i] = ~0ull;

    // slices: slice s = t>>2 in [0,96), sub = t&3
    {
        int s = t >> 2, sub = t & 3;
        int cs = cnt2[(size_t)r * XB + s];
        if (cs > cap) cs = cap;
        const unsigned* sp = cand + ((size_t)r * XB + s) * cap;
        #pragma unroll
        for (int k2 = 0; k2 < 8; k2++) {
            int i = sub + 4*k2;
            if (i < cs) {
                unsigned p = sp[i];
                unsigned jj = (p >> 7) & 31u;
                unsigned col = (unsigned)((s + (int)jj * XB) * 128) + (p & 127u);
                v[k2] = ((ull)(p & 0xFFFF0000u) << 16) | col;
            }
        }
    }
    // overflow
    {
        int oc = (int)ovcnt[r];
        if (oc > ovcap) oc = ovcap;
        #pragma unroll
        for (int k2 = 0; k2 < 2; k2++) {
            int i = t + 384*k2;
            if (i < oc) {
                ull e = ov[(size_t)r * ovcap + i];
                unsigned fs = (unsigned)(e >> 32);
                unsigned col = (unsigned)e;
                v[8+k2] = ((ull)(fs & 0xFFFF0000u) << 16) | col;
            }
        }
    }
    __syncthreads();

    for (int e = 0; e < NS; e++) {
        ull m = v[0];
        #pragma unroll
        for (int i = 1; i < 10; i++) m = (v[i] < m) ? v[i] : m;
        ull wm = m;
        #pragma unroll
        for (int mm = 1; mm < 64; mm <<= 1) {
            ull o = __shfl_xor(wm, mm, 64);
            wm = (o < wm) ? o : wm;
        }
        if ((t & 63) == 0) wred2[t >> 6] = wm;
        __syncthreads();
        ull g = wred2[0];
        #pragma unroll
        for (int i = 1; i < 6; i++) if (wred2[i] < g) g = wred2[i];
        if (m == g && g != ~0ull) {
            #pragma unroll
            for (int i = 0; i < 10; i++) if (v[i] == g) v[i] = ~0ull;
        }
        if (t == 0) win[e] = g;
        __syncthreads();
    }

    // exact fp32 recompute for NS winners
    if (t < NS) {
        ull g = win[t];
        float dv = 3.0e38f;
        unsigned idx = 0xFFFFFFFFu;
        if (g != ~0ull) {
            idx = (unsigned)g;
            const float4* kp = (const float4*)(keys + (size_t)idx * HDIM);
            float acc = 0.f;
            #pragma unroll
            for (int q = 0; q < 16; q++) {
                float4 kv = kp[q];
                acc = fmaf(hrow_s[4*q+0], kv.x, acc);
                acc = fmaf(hrow_s[4*q+1], kv.y, acc);
                acc = fmaf(hrow_s[4*q+2], kv.z, acc);
                acc = fmaf(hrow_s[4*q+3], kv.w, acc);
            }
            dv = fmaxf(hsq[r] + ksq[idx] - 2.f * acc, 0.f);
        }
        dexs[t] = dv;
        idxs[t] = idx;
    }
    __syncthreads();

    float cw = 0.f, cwv = 0.f;
    if (t < NS && idxs[t] != 0xFFFFFFFFu) {
        float dv = dexs[t];
        unsigned idx = idxs[t];
        unsigned fd = ford(dv);
        int rk = 0;
        for (int q = 0; q < NS; q++) {
            unsigned fq = ford(dexs[q]);
            rk += ((fq < fd) || (fq == fd && idxs[q] < idx)) ? 1 : 0;
        }
        if (rk < K_NB) {
            float wgt = 1.f / (dv + DELTA);
            cw = wgt;
            cwv = wgt * vals[idx];
        }
    }
    #pragma unroll
    for (int m = 1; m < 64; m <<= 1) {
        cw  += __shfl_xor(cw,  m, 64);
        cwv += __shfl_xor(cwv, m, 64);
    }
    if ((t & 63) == 0) { rs[t >> 6] = cw; rvs[t >> 6] = cwv; }
    __syncthreads();
    if (t == 0) {
        float sw = 0.f, sv = 0.f;
        #pragma unroll
        for (int i = 0; i < 6; i++) { sw += rs[i]; sv += rvs[i]; }
        out_val[r] = sv / sw;
    }
}

// ---------- launch ----------
extern "C" void kernel_launch(void* const* d_in, const int* in_sizes, int n_in,
                              void* d_out, int out_size, void* d_ws, size_t ws_size,
                              hipStream_t stream)
{
    const float* x    = (const float*)d_in[0];
    const float* W1   = (const float*)d_in[1];
    const float* b1   = (const float*)d_in[2];
    const float* Wp   = (const float*)d_in[3];
    const float* bp   = (const float*)d_in[4];
    const float* keys = (const float*)d_in[5];
    const float* vals = (const float*)d_in[6];
    float* out = (float*)d_out;
    float* ws  = (float*)d_ws;

    // ws layout (float units)
    float*          ws_h  = ws;                               // 65536
    float*          hsq   = ws + 65536;                       // 1024
    float*          ksq   = ws + 66560;                       // 200704 (padded)
    float*          thr   = ws + 267264;                      // 1024
    unsigned short* a2    = (unsigned short*)(ws + 268288);   // 65536 floats
    int*            cnt2  = (int*)(ws + 333824);              // 1024*96 = 98304
    unsigned*       ovcnt = (unsigned*)(ws + 432128);         // 1024
    const size_t basef = 433152;

    // tiers: A: sample4096/rank24/cap32/ov512; B: sample2048/rank12/cap16/ov512;
    //        C: sample2048/rank12/cap16/ov256
    int sample, rank, cap, ovcap;
    size_t candf, ovf;
    {
        const size_t needA = (basef + 3145728ull + 1048576ull) * 4ull;   // 18.5 MB
        const size_t needB = (basef + 1572864ull + 1048576ull) * 4ull;   // 12.2 MB
        if (ws_size >= needA) { sample=4096; rank=24; cap=32; ovcap=512;
                                candf=3145728; ovf=1048576; }
        else if (ws_size >= needB) { sample=2048; rank=12; cap=16; ovcap=512;
                                candf=1572864; ovf=1048576; }
        else { sample=2048; rank=12; cap=16; ovcap=256;
                                candf=1572864; ovf=524288; }
    }
    unsigned*       cand     = (unsigned*)(ws + basef);
    ull*            ov       = (ull*)(ws + basef + candf);
    unsigned short* d_sample = (unsigned short*)cand;          // overlay (dead before k_dist)

    k_mlp<<<BROWS, 64, 0, stream>>>(x, W1, b1, Wp, bp, out, ws_h, hsq, ovcnt, a2);
    k_ksq<<<NKEYS / 16, 256, 0, stream>>>(keys, ksq);
    dim3 gsd(sample / 128, 8);
    k_sdist<<<gsd, 256, 0, stream>>>(keys, a2, hsq, ksq, d_sample, sample);
    k_sel<<<BROWS / 4, 256, 0, stream>>>(d_sample, thr, sample, rank);
    dim3 gdist(XB, 8);
    k_dist<<<gdist, 256, 0, stream>>>(keys, a2, hsq, ksq, thr, cnt2, ovcnt, ov,
                                      cand, cap, ovcap);
    k_merge<<<BROWS, 384, 0, stream>>>(cand, cnt2, ovcnt, ov, vals, keys, ws_h, hsq, ksq,
                                       out + OUT_VAL_OFF, cap, ovcap);
}

// Round 6
// 432.691 us; speedup vs baseline: 1.4934x; 1.4934x over previous
//
#include <hip/hip_runtime.h>
#include <hip/hip_bf16.h>
#include <stdint.h>

#define K_NB    50
#define DELTA   1e-3f
#define NKEYS   200000
#define BROWS   1024
#define HDIM    64
#define SDIM    256
#define ADIM    18
#define SAMPLE  4096
#define RANKSEL 24
#define XB      64          // x-blocks in k_dist
#define JMAX    25          // ceil(NTILES/XB)
#define NTILES  1563        // ceil(200000/128)
#define CAP     28          // per-(row,block) candidate slots
#define SURV    192         // max survivors for exact recompute
#define TOPSEL  80          // binary-search target (covers q16 reorder of top-50)

// out layout (floats): policy [0,18432) | value [18432,19456) | h [19456,84992)
#define OUT_VAL_OFF 18432
#define OUT_H_OFF   19456

typedef __attribute__((ext_vector_type(8))) short short8;
typedef __attribute__((ext_vector_type(4))) float f32x4;
typedef unsigned long long ull;

__device__ __forceinline__ unsigned ford(float f) {
    unsigned u = __float_as_uint(f);
    return (u & 0x80000000u) ? ~u : (u | 0x80000000u);
}
__device__ __forceinline__ float funord(unsigned u) {
    u = (u & 0x80000000u) ? (u & 0x7FFFFFFFu) : ~u;
    return __uint_as_float(u);
}
__device__ __forceinline__ unsigned short bf16_rne(float f) {
    unsigned u = __float_as_uint(f);
    unsigned r = u + 0x7FFFu + ((u >> 16) & 1u);
    return (unsigned short)(r >> 16);
}
__device__ __forceinline__ float bf16_tof(unsigned short b) {
    return __uint_as_float(((unsigned)b) << 16);
}
// async global->LDS, 16B per lane; dst is wave-uniform base (+lane*16 by HW)
__device__ __forceinline__ void gld_lds16(const short8* g, const short8* l) {
    __builtin_amdgcn_global_load_lds(
        (const __attribute__((address_space(1))) void*)g,
        (__attribute__((address_space(3))) void*)l, 16, 0, 0);
}
#define SW(g, k) ((k) ^ ((g) & 7))   // bank swizzle of key-slot within granule row

// ---------- K1: h = relu(x@W1+b1), hsq, policy, A2 bf16 hi/lo, zero ovcnt ----------
__global__ __launch_bounds__(64) void k_mlp(
    const float* __restrict__ x, const float* __restrict__ W1,
    const float* __restrict__ b1, const float* __restrict__ Wp,
    const float* __restrict__ bp, float* __restrict__ out,
    float* __restrict__ ws_h, float* __restrict__ hsq,
    unsigned* __restrict__ ovcnt, unsigned short* __restrict__ a2)
{
    const int b = blockIdx.x;
    const int j = threadIdx.x;
    const float* xr = x + b * SDIM;
    float a0 = 0.f, a1 = 0.f, a2r = 0.f, a3 = 0.f;
    #pragma unroll 8
    for (int s = 0; s < SDIM; s += 4) {
        a0  = fmaf(xr[s+0], W1[(s+0)*HDIM + j], a0);
        a1  = fmaf(xr[s+1], W1[(s+1)*HDIM + j], a1);
        a2r = fmaf(xr[s+2], W1[(s+2)*HDIM + j], a2r);
        a3  = fmaf(xr[s+3], W1[(s+3)*HDIM + j], a3);
    }
    float h = (a0 + a1) + (a2r + a3) + b1[j];
    h = fmaxf(h, 0.f);
    ws_h[b*HDIM + j] = h;
    out[OUT_H_OFF + b*HDIM + j] = h;

    unsigned u = __float_as_uint(h);
    unsigned short hi = (unsigned short)(u >> 16);        // trunc split
    float lf = h - __uint_as_float(u & 0xFFFF0000u);
    unsigned short lo = bf16_rne(lf);
    a2[b*128 + j]      = hi;
    a2[b*128 + 64 + j] = lo;

    float sq = h * h;
    #pragma unroll
    for (int m = 32; m >= 1; m >>= 1) sq += __shfl_xor(sq, m, 64);
    if (j == 0) { hsq[b] = sq; ovcnt[b] = 0u; }

    __shared__ float hl[HDIM];
    hl[j] = h;
    __syncthreads();
    if (j < ADIM) {
        float p = bp[j];
        #pragma unroll 8
        for (int k = 0; k < HDIM; k++) p = fmaf(hl[k], Wp[k*ADIM + j], p);
        out[b*ADIM + j] = p;
    }
}

// ---------- K2: ksq (fallback path only) ----------
__global__ __launch_bounds__(256) void k_ksq(
    const float* __restrict__ keys, float* __restrict__ ksq)
{
    const int t = threadIdx.x;
    const int key = blockIdx.x * 16 + (t >> 4);
    const int l = t & 15;
    float4 v = *(const float4*)(keys + (size_t)key * HDIM + l * 4);
    float s = v.x*v.x + v.y*v.y + v.z*v.z + v.w*v.w;
    s += __shfl_xor(s, 1, 64);
    s += __shfl_xor(s, 2, 64);
    s += __shfl_xor(s, 4, 64);
    s += __shfl_xor(s, 8, 64);
    if (l == 0) ksq[key] = s;
}

// ---------- K-conv: keys -> kbT (tile-major, granule-major, swizzled bf16 hi/lo) + ksq ----------
// kbT[tile][g][slot] : short8; granule g<8 = hi dims [g*8,g*8+8), g>=8 = lo dims.
// slot = key_in_tile ^ (g&7)  (inverse swizzle pre-applied for linear global_load_lds)
__global__ __launch_bounds__(256) void k_conv(
    const float* __restrict__ keys, short8* __restrict__ kbT, float* __restrict__ ksq)
{
    const int tile  = blockIdx.x;
    const int t     = threadIdx.x;
    const int kk    = t >> 1;        // key within tile
    const int spart = t & 1;         // dim half
    const int gk    = tile * 128 + kk;
    const bool valid = gk < NKEYS;

    float4 f[8];
    if (valid) {
        const float4* kp = (const float4*)(keys + (size_t)gk * HDIM + spart * 32);
        #pragma unroll
        for (int i = 0; i < 8; i++) f[i] = kp[i];
    } else {
        #pragma unroll
        for (int i = 0; i < 8; i++) f[i] = make_float4(0.f,0.f,0.f,0.f);
    }

    float ss = 0.f;
    #pragma unroll
    for (int i = 0; i < 8; i++)
        ss += f[i].x*f[i].x + f[i].y*f[i].y + f[i].z*f[i].z + f[i].w*f[i].w;
    ss += __shfl_xor(ss, 1, 64);
    if (valid && spart == 0) ksq[gk] = ss;

    #pragma unroll
    for (int i = 0; i < 4; i++) {
        float fv[8] = { f[2*i].x, f[2*i].y, f[2*i].z, f[2*i].w,
                        f[2*i+1].x, f[2*i+1].y, f[2*i+1].z, f[2*i+1].w };
        short8 H, L;
        #pragma unroll
        for (int q = 0; q < 8; q++) {
            unsigned u = __float_as_uint(fv[q]);
            H[q] = (short)(u >> 16);
            float lf = fv[q] - __uint_as_float(u & 0xFFFF0000u);
            L[q] = (short)(__float_as_uint(lf) >> 16);
        }
        const int gh = spart * 4 + i;
        const int gl = 8 + spart * 4 + i;
        kbT[(((size_t)tile * 16 + gh) << 7) + SW(gh, kk)] = H;
        kbT[(((size_t)tile * 16 + gl) << 7) + SW(gl, kk)] = L;
    }
}

// ---------- shared MFMA tile core ----------
// wave w stages granules [w*4, w*4+4), both 64-key halves, into bl (linear)
__device__ __forceinline__ void stage_tile(const short8* __restrict__ kbT, int tile,
                                           int w, int lane, short8* bl)
{
    #pragma unroll
    for (int i = 0; i < 4; i++) {
        const int g = w * 4 + i;
        const short8* src = kbT + (((size_t)tile * 16 + g) << 7);
        gld_lds16(src + lane,      bl + g * 128);
        gld_lds16(src + 64 + lane, bl + g * 128 + 64);
    }
}

// ---------- K3a-g: sample distance GEMM from kbT -> u16 quantized d ----------
__global__ __launch_bounds__(256) void k_sdist_g(
    const short8* __restrict__ kbT, const unsigned short* __restrict__ a2,
    const float* __restrict__ hsq, const float* __restrict__ ksq,
    unsigned short* __restrict__ d_sample)
{
    __shared__ short8 Bl[16][128];

    const int t    = threadIdx.x;
    const int w    = t >> 6;
    const int lane = t & 63;
    const int wr0  = (w >> 1) * 64;
    const int wc0  = (w & 1) * 64;
    const int l15  = lane & 15;
    const int l4   = lane >> 4;
    const int row0 = blockIdx.y * 128;
    const int tile = blockIdx.x;          // sample tiles = first 32 tiles

    stage_tile(kbT, tile, w, lane, &Bl[0][0]);

    short8 a[4][4];
    #pragma unroll
    for (int mf = 0; mf < 4; mf++) {
        int row = row0 + wr0 + mf * 16 + l15;
        #pragma unroll
        for (int at = 0; at < 4; at++)
            a[mf][at] = *(const short8*)(a2 + (size_t)row * 128 + at * 32 + l4 * 8);
    }
    float hs_r[4][4];
    #pragma unroll
    for (int mf = 0; mf < 4; mf++)
        #pragma unroll
        for (int rg = 0; rg < 4; rg++)
            hs_r[mf][rg] = hsq[row0 + wr0 + mf*16 + l4*4 + rg];
    float kh[4];
    #pragma unroll
    for (int nf = 0; nf < 4; nf++)
        kh[nf] = 0.5f * ksq[tile * 128 + wc0 + nf * 16 + l15];

    __syncthreads();   // staging complete (drains vmcnt)

    f32x4 acc[4][4];
    #pragma unroll
    for (int mf = 0; mf < 4; mf++)
        #pragma unroll
        for (int nf = 0; nf < 4; nf++)
            acc[mf][nf] = (f32x4){0.f,0.f,0.f,0.f};

    #pragma unroll
    for (int bt = 0; bt < 4; bt++) {
        short8 bf[4];
        #pragma unroll
        for (int nf = 0; nf < 4; nf++) {
            const int g = bt*4 + l4;
            bf[nf] = Bl[g][SW(g, wc0 + nf*16 + l15)];
        }
        const int at0 = (bt < 2) ? bt : (bt - 2);
        #pragma unroll
        for (int mf = 0; mf < 4; mf++)
            #pragma unroll
            for (int nf = 0; nf < 4; nf++)
                acc[mf][nf] = __builtin_amdgcn_mfma_f32_16x16x32_bf16(
                    a[mf][at0], bf[nf], acc[mf][nf], 0, 0, 0);
        if (bt < 2) {
            const int at1 = bt + 2;
            #pragma unroll
            for (int mf = 0; mf < 4; mf++)
                #pragma unroll
                for (int nf = 0; nf < 4; nf++)
                    acc[mf][nf] = __builtin_amdgcn_mfma_f32_16x16x32_bf16(
                        a[mf][at1], bf[nf], acc[mf][nf], 0, 0, 0);
        }
    }

    #pragma unroll
    for (int mf = 0; mf < 4; mf++)
        #pragma unroll
        for (int nf = 0; nf < 4; nf++)
            #pragma unroll
            for (int rg = 0; rg < 4; rg++) {
                int row = row0 + wr0 + mf*16 + l4*4 + rg;
                int col = tile*128 + wc0 + nf*16 + l15;
                float s = kh[nf] - acc[mf][nf][rg];
                float d = fmaf(2.f, s, hs_r[mf][rg]);
                d_sample[(size_t)row * SAMPLE + col] = (unsigned short)(ford(d) >> 16);
            }
}

// ---------- K3a-r: fallback sample GEMM (reads keys, converts inline) ----------
__global__ __launch_bounds__(256, 2) void k_sdist_r(
    const float* __restrict__ keys, const unsigned short* __restrict__ a2,
    const float* __restrict__ hsq, const float* __restrict__ ksq,
    unsigned short* __restrict__ d_sample)
{
    __shared__ short8 Bl[16][130];

    const int t    = threadIdx.x;
    const int w    = t >> 6;
    const int lane = t & 63;
    const int wr0  = (w >> 1) * 64;
    const int wc0  = (w & 1) * 64;
    const int l15  = lane & 15;
    const int l4   = lane >> 4;
    const int row0 = blockIdx.y * 128;
    const int n0   = blockIdx.x * 128;

    short8 a[4][4];
    #pragma unroll
    for (int mf = 0; mf < 4; mf++) {
        int row = row0 + wr0 + mf * 16 + l15;
        #pragma unroll
        for (int at = 0; at < 4; at++)
            a[mf][at] = *(const short8*)(a2 + (size_t)row * 128 + at * 32 + l4 * 8);
    }
    float hs_r[4][4];
    #pragma unroll
    for (int mf = 0; mf < 4; mf++)
        #pragma unroll
        for (int rg = 0; rg < 4; rg++)
            hs_r[mf][rg] = hsq[row0 + wr0 + mf*16 + l4*4 + rg];

    const int skey  = t >> 1;
    const int spart = t & 1;
    float4 f[8];
    {
        const float4* kp = (const float4*)(keys + (size_t)(n0 + skey) * HDIM + spart * 32);
        #pragma unroll
        for (int i = 0; i < 8; i++) f[i] = kp[i];
    }
    #pragma unroll
    for (int i = 0; i < 4; i++) {
        float fv[8] = { f[2*i].x, f[2*i].y, f[2*i].z, f[2*i].w,
                        f[2*i+1].x, f[2*i+1].y, f[2*i+1].z, f[2*i+1].w };
        short8 H, L;
        #pragma unroll
        for (int q = 0; q < 8; q++) {
            unsigned u = __float_as_uint(fv[q]);
            H[q] = (short)(u >> 16);
            float lf = fv[q] - __uint_as_float(u & 0xFFFF0000u);
            L[q] = (short)(__float_as_uint(lf) >> 16);
        }
        Bl[spart*4 + i][skey]     = H;
        Bl[8 + spart*4 + i][skey] = L;
    }
    __syncthreads();

    float kh[4];
    #pragma unroll
    for (int nf = 0; nf < 4; nf++)
        kh[nf] = 0.5f * ksq[n0 + wc0 + nf * 16 + l15];

    f32x4 acc[4][4];
    #pragma unroll
    for (int mf = 0; mf < 4; mf++)
        #pragma unroll
        for (int nf = 0; nf < 4; nf++)
            acc[mf][nf] = (f32x4){0.f,0.f,0.f,0.f};

    #pragma unroll
    for (int bt = 0; bt < 4; bt++) {
        short8 bf[4];
        #pragma unroll
        for (int nf = 0; nf < 4; nf++)
            bf[nf] = Bl[bt*4 + l4][wc0 + nf*16 + l15];
        const int at0 = (bt < 2) ? bt : (bt - 2);
        #pragma unroll
        for (int mf = 0; mf < 4; mf++)
            #pragma unroll
            for (int nf = 0; nf < 4; nf++)
                acc[mf][nf] = __builtin_amdgcn_mfma_f32_16x16x32_bf16(
                    a[mf][at0], bf[nf], acc[mf][nf], 0, 0, 0);
        if (bt < 2) {
            const int at1 = bt + 2;
            #pragma unroll
            for (int mf = 0; mf < 4; mf++)
                #pragma unroll
                for (int nf = 0; nf < 4; nf++)
                    acc[mf][nf] = __builtin_amdgcn_mfma_f32_16x16x32_bf16(
                        a[mf][at1], bf[nf], acc[mf][nf], 0, 0, 0);
        }
    }

    #pragma unroll
    for (int mf = 0; mf < 4; mf++)
        #pragma unroll
        for (int nf = 0; nf < 4; nf++)
            #pragma unroll
            for (int rg = 0; rg < 4; rg++) {
                int row = row0 + wr0 + mf*16 + l4*4 + rg;
                int col = n0 + wc0 + nf*16 + l15;
                float s = kh[nf] - acc[mf][nf][rg];
                float d = fmaf(2.f, s, hs_r[mf][rg]);
                d_sample[(size_t)row * SAMPLE + col] = (unsigned short)(ford(d) >> 16);
            }
}

// ---------- K3b: rank-select threshold from quantized sample distances ----------
__global__ __launch_bounds__(256) void k_sel(
    const unsigned short* __restrict__ d_sample, float* __restrict__ thr)
{
    __shared__ unsigned sbuf[4][2048];
    const int t = threadIdx.x;
    const int wv = t >> 6;
    const int l = t & 63;
    const int row = blockIdx.x * 4 + wv;

    const uint4* gp = (const uint4*)(d_sample + (size_t)row * SAMPLE);
    #pragma unroll
    for (int q = 0; q < 8; q++) {
        uint4 vv = gp[l + 64*q];
        int bidx = (l + 64*q) * 4;
        sbuf[wv][bidx+0] = vv.x; sbuf[wv][bidx+1] = vv.y;
        sbuf[wv][bidx+2] = vv.z; sbuf[wv][bidx+3] = vv.w;
    }
    __syncthreads();

    float tval = 0.f;
    for (int it = 0; it < RANKSEL; it++) {
        unsigned best = 0xFFFFFFFFu;
        #pragma unroll
        for (int m = 0; m < 32; m++) {
            unsigned wd = sbuf[wv][l + 64*m];
            unsigned slot2 = (unsigned)((l + 64*m) * 2);
            unsigned klo = ((wd & 0xFFFFu) << 12) | slot2;
            unsigned khi = ((wd >> 16) << 12) | (slot2 + 1);
            unsigned kk = (klo < khi) ? klo : khi;
            best = (kk < best) ? kk : best;
        }
        #pragma unroll
        for (int m = 1; m < 64; m <<= 1) {
            unsigned o = __shfl_xor(best, m, 64);
            best = (o < best) ? o : best;
        }
        if (l == 0) {
            unsigned slot = best & 0xFFFu;
            unsigned wd = sbuf[wv][slot >> 1];
            wd |= (slot & 1) ? 0xFFFF0000u : 0x0000FFFFu;
            sbuf[wv][slot >> 1] = wd;
        }
        if (it == RANKSEL - 1) tval = funord((best >> 12) << 16);
        __syncthreads();
    }
    if (l == 0) thr[row] = tval;
}

// ---------- K4-g: m97-style MFMA GEMM: gload_lds double-buffer, ONE barrier/tile ----------
__global__ __launch_bounds__(256, 2) void k_dist_g(
    const short8* __restrict__ kbT, const unsigned short* __restrict__ a2,
    const float* __restrict__ hsq, const float* __restrict__ ksq,
    const float* __restrict__ thr, int* __restrict__ cnt2,
    unsigned* __restrict__ ovcnt, ull* __restrict__ ov,
    unsigned* __restrict__ cand, int ovcap)
{
    __shared__ short8 Bl[2][16][128];          // 65536 B
    __shared__ unsigned cand_lds[128 * 32];    // 16384 B (stride 32, cap 28)
    __shared__ unsigned lds_cnt[128];          // 512 B -> 82432 B total? (see LDS note)

    const int t    = threadIdx.x;
    const int w    = t >> 6;
    const int lane = t & 63;
    const int wr0  = (w >> 1) * 64;
    const int wc0  = (w & 1) * 64;
    const int l15  = lane & 15;
    const int l4   = lane >> 4;
    const int row0 = blockIdx.y * 128;
    const int bx   = blockIdx.x;

    if (t < 128) lds_cnt[t] = 0u;

    short8 a[4][4];
    #pragma unroll
    for (int mf = 0; mf < 4; mf++) {
        int row = row0 + wr0 + mf * 16 + l15;
        #pragma unroll
        for (int at = 0; at < 4; at++)
            a[mf][at] = *(const short8*)(a2 + (size_t)row * 128 + at * 32 + l4 * 8);
    }
    float lim[4][4];
    #pragma unroll
    for (int mf = 0; mf < 4; mf++)
        #pragma unroll
        for (int rg = 0; rg < 4; rg++) {
            int r = row0 + wr0 + mf * 16 + l4 * 4 + rg;
            lim[mf][rg] = (thr[r] - hsq[r]) * 0.5f;
        }

    stage_tile(kbT, bx, w, lane, &Bl[0][0][0]);
    __syncthreads();                    // tile0 staged

    for (int j = 0; j < JMAX; j++) {
        const int cur = bx + j * XB;
        if (cur >= NTILES) break;
        const int b = j & 1;

        // issue next tile's staging into the other buffer (fire & forget)
        const int nxt = cur + XB;
        if (nxt < NTILES)
            stage_tile(kbT, nxt, w, lane, &Bl[b ^ 1][0][0]);

        float kh[4];
        #pragma unroll
        for (int nf = 0; nf < 4; nf++) {
            int col = cur * 128 + wc0 + nf * 16 + l15;
            kh[nf] = (col < NKEYS) ? 0.5f * ksq[col] : 3.0e37f;
        }

        f32x4 acc[4][4];
        #pragma unroll
        for (int mf = 0; mf < 4; mf++)
            #pragma unroll
            for (int nf = 0; nf < 4; nf++)
                acc[mf][nf] = (f32x4){0.f,0.f,0.f,0.f};

        #pragma unroll
        for (int bt = 0; bt < 4; bt++) {
            short8 bf[4];
            #pragma unroll
            for (int nf = 0; nf < 4; nf++) {
                const int g = bt*4 + l4;
                bf[nf] = Bl[b][g][SW(g, wc0 + nf*16 + l15)];
            }
            const int at0 = (bt < 2) ? bt : (bt - 2);
            #pragma unroll
            for (int mf = 0; mf < 4; mf++)
                #pragma unroll
                for (int nf = 0; nf < 4; nf++)
                    acc[mf][nf] = __builtin_amdgcn_mfma_f32_16x16x32_bf16(
                        a[mf][at0], bf[nf], acc[mf][nf], 0, 0, 0);
            if (bt < 2) {
                const int at1 = bt + 2;
                #pragma unroll
                for (int mf = 0; mf < 4; mf++)
                    #pragma unroll
                    for (int nf = 0; nf < 4; nf++)
                        acc[mf][nf] = __builtin_amdgcn_mfma_f32_16x16x32_bf16(
                            a[mf][at1], bf[nf], acc[mf][nf], 0, 0, 0);
            }
        }

        // epilogue: per-lane LDS-atomic append
        #pragma unroll
        for (int mf = 0; mf < 4; mf++)
            #pragma unroll
            for (int nf = 0; nf < 4; nf++)
                #pragma unroll
                for (int rg = 0; rg < 4; rg++) {
                    float s = kh[nf] - acc[mf][nf][rg];
                    if (s < lim[mf][rg]) {
                        int lrow = wr0 + mf*16 + l4*4 + rg;
                        unsigned pos = atomicAdd(&lds_cnt[lrow], 1u);
                        if (pos < (unsigned)CAP) {
                            unsigned packed = (ford(s) & 0xFFFF0000u)
                                            | ((unsigned)j << 7)
                                            | (unsigned)(wc0 + nf*16 + l15);
                            cand_lds[lrow * 32 + pos] = packed;
                        } else {
                            int grow = row0 + lrow;
                            unsigned p2 = atomicAdd(&ovcnt[grow], 1u);
                            if (p2 < (unsigned)ovcap)
                                ov[(size_t)grow * ovcap + p2] =
                                    ((ull)ford(s) << 32) | (unsigned)(cur*128 + wc0 + nf*16 + l15);
                        }
                    }
                }

        __syncthreads();   // staging for nxt complete + all waves done with Bl[b]
    }

    __syncthreads();
    if (t < 128) {
        unsigned c = lds_cnt[t];
        if (c > (unsigned)CAP) c = (unsigned)CAP;
        cnt2[(size_t)(row0 + t) * XB + bx] = (int)c;
        unsigned* dst = cand + ((size_t)(row0 + t) * XB + bx) * CAP;
        const unsigned* src = &cand_lds[t * 32];
        #pragma unroll
        for (int i = 0; i < 7; i++)
            ((uint4*)dst)[i] = *(const uint4*)&src[i * 4];
    }
}

// ---------- K4-r: fallback (reg-staged, convert in loop; r5 structure, XB=64) ----------
__global__ __launch_bounds__(256, 2) void k_dist_r(
    const float* __restrict__ keys, const unsigned short* __restrict__ a2,
    const float* __restrict__ hsq, const float* __restrict__ ksq,
    const float* __restrict__ thr, int* __restrict__ cnt2,
    unsigned* __restrict__ ovcnt, ull* __restrict__ ov,
    unsigned* __restrict__ cand, int ovcap)
{
    __shared__ short8 Bl[16][130];
    __shared__ unsigned cand_lds[128 * 32];
    __shared__ unsigned lds_cnt[128];

    const int t    = threadIdx.x;
    const int w    = t >> 6;
    const int lane = t & 63;
    const int wr0  = (w >> 1) * 64;
    const int wc0  = (w & 1) * 64;
    const int l15  = lane & 15;
    const int l4   = lane >> 4;
    const int row0 = blockIdx.y * 128;
    const int bx   = blockIdx.x;

    if (t < 128) lds_cnt[t] = 0u;

    short8 a[4][4];
    #pragma unroll
    for (int mf = 0; mf < 4; mf++) {
        int row = row0 + wr0 + mf * 16 + l15;
        #pragma unroll
        for (int at = 0; at < 4; at++)
            a[mf][at] = *(const short8*)(a2 + (size_t)row * 128 + at * 32 + l4 * 8);
    }
    float lim[4][4];
    #pragma unroll
    for (int mf = 0; mf < 4; mf++)
        #pragma unroll
        for (int rg = 0; rg < 4; rg++) {
            int r = row0 + wr0 + mf * 16 + l4 * 4 + rg;
            lim[mf][rg] = (thr[r] - hsq[r]) * 0.5f;
        }

    const int skey  = t >> 1;
    const int spart = t & 1;
    float4 f[8];
    {
        const float4* kp = (const float4*)(keys + (size_t)(bx * 128 + skey) * HDIM + spart * 32);
        #pragma unroll
        for (int i = 0; i < 8; i++) f[i] = kp[i];
    }

    for (int j = 0; j < JMAX; j++) {
        const int cur = bx + j * XB;
        if (cur >= NTILES) break;

        short8 Hh[4], Ll[4];
        #pragma unroll
        for (int i = 0; i < 4; i++) {
            float fv[8] = { f[2*i].x, f[2*i].y, f[2*i].z, f[2*i].w,
                            f[2*i+1].x, f[2*i+1].y, f[2*i+1].z, f[2*i+1].w };
            #pragma unroll
            for (int q = 0; q < 8; q++) {
                unsigned u = __float_as_uint(fv[q]);
                Hh[i][q] = (short)(u >> 16);
                float lf = fv[q] - __uint_as_float(u & 0xFFFF0000u);
                Ll[i][q] = (short)(__float_as_uint(lf) >> 16);
            }
        }

        __syncthreads();
        #pragma unroll
        for (int i = 0; i < 4; i++) {
            Bl[spart*4 + i][skey]     = Hh[i];
            Bl[8 + spart*4 + i][skey] = Ll[i];
        }
        __syncthreads();

        {
            int nxt = cur + XB;
            if (nxt < NTILES) {
                int kg = nxt * 128 + skey;
                if (kg < NKEYS) {
                    const float4* kp = (const float4*)(keys + (size_t)kg * HDIM + spart * 32);
                    #pragma unroll
                    for (int i = 0; i < 8; i++) f[i] = kp[i];
                } else {
                    #pragma unroll
                    for (int i = 0; i < 8; i++) f[i] = make_float4(0.f,0.f,0.f,0.f);
                }
            }
        }

        float kh[4];
        #pragma unroll
        for (int nf = 0; nf < 4; nf++) {
            int col = cur * 128 + wc0 + nf * 16 + l15;
            kh[nf] = (col < NKEYS) ? 0.5f * ksq[col] : 3.0e37f;
        }

        f32x4 acc[4][4];
        #pragma unroll
        for (int mf = 0; mf < 4; mf++)
            #pragma unroll
            for (int nf = 0; nf < 4; nf++)
                acc[mf][nf] = (f32x4){0.f,0.f,0.f,0.f};

        #pragma unroll
        for (int bt = 0; bt < 4; bt++) {
            short8 bf[4];
            #pragma unroll
            for (int nf = 0; nf < 4; nf++)
                bf[nf] = Bl[bt*4 + l4][wc0 + nf*16 + l15];
            const int at0 = (bt < 2) ? bt : (bt - 2);
            #pragma unroll
            for (int mf = 0; mf < 4; mf++)
                #pragma unroll
                for (int nf = 0; nf < 4; nf++)
                    acc[mf][nf] = __builtin_amdgcn_mfma_f32_16x16x32_bf16(
                        a[mf][at0], bf[nf], acc[mf][nf], 0, 0, 0);
            if (bt < 2) {
                const int at1 = bt + 2;
                #pragma unroll
                for (int mf = 0; mf < 4; mf++)
                    #pragma unroll
                    for (int nf = 0; nf < 4; nf++)
                        acc[mf][nf] = __builtin_amdgcn_mfma_f32_16x16x32_bf16(
                            a[mf][at1], bf[nf], acc[mf][nf], 0, 0, 0);
            }
        }

        #pragma unroll
        for (int mf = 0; mf < 4; mf++)
            #pragma unroll
            for (int nf = 0; nf < 4; nf++)
                #pragma unroll
                for (int rg = 0; rg < 4; rg++) {
                    float s = kh[nf] - acc[mf][nf][rg];
                    if (s < lim[mf][rg]) {
                        int lrow = wr0 + mf*16 + l4*4 + rg;
                        unsigned pos = atomicAdd(&lds_cnt[lrow], 1u);
                        if (pos < (unsigned)CAP) {
                            unsigned packed = (ford(s) & 0xFFFF0000u)
                                            | ((unsigned)j << 7)
                                            | (unsigned)(wc0 + nf*16 + l15);
                            cand_lds[lrow * 32 + pos] = packed;
                        } else {
                            int grow = row0 + lrow;
                            unsigned p2 = atomicAdd(&ovcnt[grow], 1u);
                            if (p2 < (unsigned)ovcap)
                                ov[(size_t)grow * ovcap + p2] =
                                    ((ull)ford(s) << 32) | (unsigned)(cur*128 + wc0 + nf*16 + l15);
                        }
                    }
                }
    }

    __syncthreads();
    if (t < 128) {
        unsigned c = lds_cnt[t];
        if (c > (unsigned)CAP) c = (unsigned)CAP;
        cnt2[(size_t)(row0 + t) * XB + bx] = (int)c;
        unsigned* dst = cand + ((size_t)(row0 + t) * XB + bx) * CAP;
        const unsigned* src = &cand_lds[t * 32];
        #pragma unroll
        for (int i = 0; i < 7; i++)
            ((uint4*)dst)[i] = *(const uint4*)&src[i * 4];
    }
}

// ---------- K5: binary-search cutoff -> exact recompute -> exact top-50 ----------
__global__ __launch_bounds__(256) void k_merge(
    const unsigned* __restrict__ cand, const int* __restrict__ cnt2,
    const unsigned* __restrict__ ovcnt, const ull* __restrict__ ov,
    const float* __restrict__ vals, const float* __restrict__ keys,
    const float* __restrict__ ws_h, const float* __restrict__ hsq,
    const float* __restrict__ ksq, float* __restrict__ out_val, int ovcap)
{
    __shared__ float hrow_s[HDIM];
    __shared__ int pcnt[16];
    __shared__ unsigned nsurv;
    __shared__ unsigned scol[SURV];
    __shared__ float dex[SURV];
    __shared__ float rs[4], rvs[4];

    const int r = blockIdx.x;
    const int t = threadIdx.x;

    if (t < HDIM) hrow_s[t] = ws_h[(size_t)r * HDIM + t];
    if (t < 16) pcnt[t] = 0;
    if (t == 0) nsurv = 0u;

    // gather candidates into regs: key16 in bits[47:32], col in [31:0]
    ull v[11];
    #pragma unroll
    for (int i = 0; i < 11; i++) v[i] = ~0ull;
    {
        int s = t >> 2, sub = t & 3;
        int cs = cnt2[(size_t)r * XB + s];
        if (cs > CAP) cs = CAP;
        const unsigned* sp = cand + ((size_t)r * XB + s) * CAP;
        #pragma unroll
        for (int k2 = 0; k2 < 7; k2++) {
            int i = sub + 4*k2;
            if (i < cs) {
                unsigned p = sp[i];
                unsigned jj = (p >> 7) & 31u;
                unsigned col = (unsigned)((s + (int)jj * XB) * 128) + (p & 127u);
                v[k2] = ((ull)(p & 0xFFFF0000u) << 16) | col;
            }
        }
    }
    {
        int oc = (int)ovcnt[r];
        if (oc > ovcap) oc = ovcap;
        #pragma unroll
        for (int k2 = 0; k2 < 4; k2++) {
            int i = t + 256*k2;
            if (i < oc) {
                ull e = ov[(size_t)r * ovcap + i];
                v[7+k2] = ((ull)((unsigned)(e >> 32) & 0xFFFF0000u) << 16) | (unsigned)e;
            }
        }
    }
    __syncthreads();

    // 16-probe binary search: smallest cutoff with count >= TOPSEL
    unsigned lo = 0, hi = 0xFFFFu;
    for (int it = 0; it < 16; it++) {
        unsigned m = (lo + hi) >> 1;
        int c = 0;
        #pragma unroll
        for (int i = 0; i < 11; i++)
            c += (v[i] != ~0ull && (unsigned)((v[i] >> 32) & 0xFFFFu) <= m) ? 1 : 0;
        #pragma unroll
        for (int mm = 1; mm < 64; mm <<= 1) c += __shfl_xor(c, mm, 64);
        if ((t & 63) == 0) atomicAdd(&pcnt[it], c);
        __syncthreads();
        int total = pcnt[it];
        if (total >= TOPSEL) hi = m; else lo = m + 1;
    }
    const unsigned cutoff = hi;

    // emit survivors
    #pragma unroll
    for (int i = 0; i < 11; i++) {
        if (v[i] != ~0ull && (unsigned)((v[i] >> 32) & 0xFFFFu) <= cutoff) {
            unsigned pos = atomicAdd(&nsurv, 1u);
            if (pos < (unsigned)SURV) scol[pos] = (unsigned)v[i];
        }
    }
    __syncthreads();
    const int ns = (int)min(nsurv, (unsigned)SURV);

    // exact fp32 recompute
    if (t < ns) {
        unsigned idx = scol[t];
        const float4* kp = (const float4*)(keys + (size_t)idx * HDIM);
        float acc = 0.f;
        #pragma unroll
        for (int q = 0; q < 16; q++) {
            float4 kv = kp[q];
            acc = fmaf(hrow_s[4*q+0], kv.x, acc);
            acc = fmaf(hrow_s[4*q+1], kv.y, acc);
            acc = fmaf(hrow_s[4*q+2], kv.z, acc);
            acc = fmaf(hrow_s[4*q+3], kv.w, acc);
        }
        dex[t] = fmaxf(hsq[r] + ksq[idx] - 2.f * acc, 0.f);
    }
    __syncthreads();

    // exact rank + weighted sum
    float cw = 0.f, cwv = 0.f;
    if (t < ns) {
        float dv = dex[t];
        unsigned idx = scol[t];
        int rk = 0;
        for (int q = 0; q < ns; q++) {
            float dq = dex[q];
            rk += ((dq < dv) || (dq == dv && scol[q] < idx)) ? 1 : 0;
        }
        if (rk < K_NB) {
            float wgt = 1.f / (dv + DELTA);
            cw = wgt;
            cwv = wgt * vals[idx];
        }
    }
    #pragma unroll
    for (int m = 1; m < 64; m <<= 1) {
        cw  += __shfl_xor(cw,  m, 64);
        cwv += __shfl_xor(cwv, m, 64);
    }
    if ((t & 63) == 0) { rs[t >> 6] = cw; rvs[t >> 6] = cwv; }
    __syncthreads();
    if (t == 0) {
        float sw = rs[0] + rs[1] + rs[2] + rs[3];
        float sv = rvs[0] + rvs[1] + rvs[2] + rvs[3];
        out_val[r] = sv / sw;
    }
}

// ---------- launch ----------
extern "C" void kernel_launch(void* const* d_in, const int* in_sizes, int n_in,
                              void* d_out, int out_size, void* d_ws, size_t ws_size,
                              hipStream_t stream)
{
    const float* x    = (const float*)d_in[0];
    const float* W1   = (const float*)d_in[1];
    const float* b1   = (const float*)d_in[2];
    const float* Wp   = (const float*)d_in[3];
    const float* bp   = (const float*)d_in[4];
    const float* keys = (const float*)d_in[5];
    const float* vals = (const float*)d_in[6];
    float* out = (float*)d_out;
    float* ws  = (float*)d_ws;

    // ws layout (float units)
    float*          ws_h  = ws;                               // 65536
    float*          hsq   = ws + 65536;                       // 1024
    float*          ksq   = ws + 66560;                       // 200704
    float*          thr   = ws + 267264;                      // 1024
    unsigned short* a2    = (unsigned short*)(ws + 268288);   // 65536 floats
    int*            cnt2  = (int*)(ws + 333824);              // 65536
    unsigned*       ovcnt = (unsigned*)(ws + 399360);         // 1024
    const size_t basef = 400384;

    const size_t candf = (size_t)BROWS * XB * CAP / 1;        // 1,835,008 u32
    unsigned* cand = (unsigned*)(ws + basef);

    // tiers
    const size_t kbTf = (size_t)NTILES * 16 * 128 * 4;        // 12,804,096 floats
    size_t ov1024f = (size_t)BROWS * 1024 * 2;                // 2,097,152
    size_t ov256f  = (size_t)BROWS * 256 * 2;                 // 524,288
    const size_t needG  = (basef + candf + ov1024f + kbTf) * 4ull;   // ~68.6 MB
    const size_t needF1 = (basef + candf + ov1024f) * 4ull;          // ~17.3 MB
    const size_t needF2 = (basef + candf + ov256f) * 4ull;           // ~11.0 MB

    int ovcap;
    bool gpath;
    if (ws_size >= needG)       { gpath = true;  ovcap = 1024; }
    else if (ws_size >= needF1) { gpath = false; ovcap = 1024; }
    else                        { gpath = false; ovcap = 256;  }
    size_t ovf = (size_t)BROWS * ovcap * 2;

    ull*            ov       = (ull*)(ws + basef + candf);
    short8*         kbT      = (short8*)(ws + basef + candf + ovf);
    unsigned short* d_sample = (unsigned short*)cand;          // overlay (dead before k_dist)

    k_mlp<<<BROWS, 64, 0, stream>>>(x, W1, b1, Wp, bp, out, ws_h, hsq, ovcnt, a2);

    dim3 gsd(SAMPLE / 128, 8);
    dim3 gdist(XB, 8);
    if (gpath) {
        k_conv<<<NTILES, 256, 0, stream>>>(keys, kbT, ksq);
        k_sdist_g<<<gsd, 256, 0, stream>>>(kbT, a2, hsq, ksq, d_sample);
        k_sel<<<BROWS / 4, 256, 0, stream>>>(d_sample, thr);
        k_dist_g<<<gdist, 256, 0, stream>>>(kbT, a2, hsq, ksq, thr, cnt2, ovcnt, ov,
                                            cand, ovcap);
    } else {
        k_ksq<<<NKEYS / 16, 256, 0, stream>>>(keys, ksq);
        k_sdist_r<<<gsd, 256, 0, stream>>>(keys, a2, hsq, ksq, d_sample);
        k_sel<<<BROWS / 4, 256, 0, stream>>>(d_sample, thr);
        k_dist_r<<<gdist, 256, 0, stream>>>(keys, a2, hsq, ksq, thr, cnt2, ovcnt, ov,
                                            cand, ovcap);
    }
    k_merge<<<BROWS, 256, 0, stream>>>(cand, cnt2, ovcnt, ov, vals, keys, ws_h, hsq, ksq,
                                       out + OUT_VAL_OFF, ovcap);
}